// Round 1
// baseline (1158.212 us; speedup 1.0000x reference)
//
#include <hip/hip_runtime.h>

#define NN 50000
#define NE 600000
#define LN_EPS 1e-5f

// ---------------------------------------------------------------------------
// K1: per-node message  m[n] = s * (LN(x[n] @ W.T + Wb) * ln_g + ln_b)
//     s = sigmoid(gamma[t]) * (1 - sigmoid(eta[t]))   (gates folded in)
// Block = 256 threads (4 waves). Each wave handles 8 nodes; each lane owns
// output columns {lane, lane+64}. W (64KB) staged in LDS, XOR-swizzled at
// float4 granularity so the per-lane row reads are bank-conflict-free.
// LN reduction is in-wave shfl_xor only (no cross-wave traffic).
// ---------------------------------------------------------------------------
__global__ __launch_bounds__(256)
void node_msg_kernel(const float* __restrict__ x, const float* __restrict__ Ww,
                     const float* __restrict__ Wb, const float* __restrict__ lng,
                     const float* __restrict__ lnb, const int* __restrict__ ts,
                     const float* __restrict__ gam, const float* __restrict__ eta,
                     float* __restrict__ m)
{
    __shared__ float Ws[128 * 128];              // exactly 64 KiB
    float4* Ws4 = reinterpret_cast<float4*>(Ws);
    const float4* Wg4 = reinterpret_cast<const float4*>(Ww);
    const int t = threadIdx.x;

    #pragma unroll
    for (int i = 0; i < 16; ++i) {
        int idx = i * 256 + t;                   // 0..4095 float4s
        int j = idx >> 5, k4 = idx & 31;         // row j, col-chunk k4
        Ws4[(j << 5) | (k4 ^ (j & 31))] = Wg4[idx];
    }
    __syncthreads();

    const int lane  = t & 63;
    const int w     = __builtin_amdgcn_readfirstlane(t >> 6);
    const int node0 = blockIdx.x * 32 + w * 8;

    const float4* x4 = reinterpret_cast<const float4*>(x);
    const float4* xp[8];
    #pragma unroll
    for (int nn = 0; nn < 8; ++nn) {
        int n = node0 + nn; if (n > NN - 1) n = NN - 1;  // clamp; store guarded
        xp[nn] = x4 + (size_t)n * 32;
    }

    float a0[8], a1[8];
    #pragma unroll
    for (int nn = 0; nn < 8; ++nn) { a0[nn] = 0.f; a1[nn] = 0.f; }

    const int sw = lane & 31;
    #pragma unroll 2
    for (int k4 = 0; k4 < 32; ++k4) {
        float4 w0 = Ws4[(lane << 5)        | (k4 ^ sw)];
        float4 w1 = Ws4[((lane + 64) << 5) | (k4 ^ sw)];
        #pragma unroll
        for (int nn = 0; nn < 8; ++nn) {
            float4 xv = xp[nn][k4];              // wave-uniform broadcast load
            a0[nn] += w0.x * xv.x + w0.y * xv.y + w0.z * xv.z + w0.w * xv.w;
            a1[nn] += w1.x * xv.x + w1.y * xv.y + w1.z * xv.z + w1.w * xv.w;
        }
    }

    const int tstep = ts[0];
    const float gsig = 1.f / (1.f + __expf(-gam[tstep]));
    const float esig = 1.f / (1.f + __expf(-eta[tstep]));
    const float sgate = gsig * (1.f - esig);

    const float b0 = Wb[lane],  b1 = Wb[lane + 64];
    const float g0 = lng[lane], g1 = lng[lane + 64];
    const float e0 = lnb[lane], e1 = lnb[lane + 64];

    #pragma unroll
    for (int nn = 0; nn < 8; ++nn) {
        float h0 = a0[nn] + b0, h1 = a1[nn] + b1;
        float r = h0 + h1, r2 = h0 * h0 + h1 * h1;
        #pragma unroll
        for (int mk = 1; mk < 64; mk <<= 1) {
            r  += __shfl_xor(r,  mk, 64);
            r2 += __shfl_xor(r2, mk, 64);
        }
        float mu  = r * (1.f / 128.f);
        float var = r2 * (1.f / 128.f) - mu * mu;
        float rs  = rsqrtf(var + LN_EPS);
        int n = node0 + nn;
        if (n < NN) {
            m[(size_t)n * 128 + lane]      = sgate * ((h0 - mu) * rs * g0 + e0);
            m[(size_t)n * 128 + lane + 64] = sgate * ((h1 - mu) * rs * g1 + e1);
        }
    }
}

// ---------------------------------------------------------------------------
// K2: agg[dst] += m[src]   (32 threads/edge, float4 gather + 4x f32 atomicAdd)
// ---------------------------------------------------------------------------
__global__ __launch_bounds__(256)
void edge_scatter_kernel(const float* __restrict__ m, const int* __restrict__ src,
                         const int* __restrict__ dst, float* __restrict__ agg)
{
    int gid = blockIdx.x * 256 + threadIdx.x;
    int e = gid >> 5, c = gid & 31;
    if (e >= NE) return;
    int s = src[e], d = dst[e];
    float4 v = reinterpret_cast<const float4*>(m)[(size_t)s * 32 + c];
    float* ap = agg + (size_t)d * 128 + (size_t)c * 4;
    atomicAdd(ap + 0, v.x);
    atomicAdd(ap + 1, v.y);
    atomicAdd(ap + 2, v.z);
    atomicAdd(ap + 3, v.w);
}

// ---------------------------------------------------------------------------
// K3: u = relu(x + agg + xi*local)   (elementwise, float4)
// ---------------------------------------------------------------------------
__global__ __launch_bounds__(256)
void upd_kernel(const float* __restrict__ x, const float* __restrict__ agg,
                const float* __restrict__ local, const float* __restrict__ xi,
                float* __restrict__ u)
{
    int i = blockIdx.x * 256 + threadIdx.x;      // float4 index
    if (i >= NN * 32) return;
    float xiv = xi[0];
    float4 xv = reinterpret_cast<const float4*>(x)[i];
    float4 av = reinterpret_cast<const float4*>(agg)[i];
    float4 lv = reinterpret_cast<const float4*>(local)[i];
    float4 r;
    r.x = fmaxf(xv.x + av.x + xiv * lv.x, 0.f);
    r.y = fmaxf(xv.y + av.y + xiv * lv.y, 0.f);
    r.z = fmaxf(xv.z + av.z + xiv * lv.z, 0.f);
    r.w = fmaxf(xv.w + av.w + xiv * lv.w, 0.f);
    reinterpret_cast<float4*>(u)[i] = r;
}

// ---------------------------------------------------------------------------
// K4: out = u @ out_w.T + out_b + u   (same structure as K1, no LN)
// ---------------------------------------------------------------------------
__global__ __launch_bounds__(256)
void out_gemm_kernel(const float* __restrict__ u, const float* __restrict__ Ow,
                     const float* __restrict__ Ob, float* __restrict__ out)
{
    __shared__ float Ws[128 * 128];
    float4* Ws4 = reinterpret_cast<float4*>(Ws);
    const float4* Wg4 = reinterpret_cast<const float4*>(Ow);
    const int t = threadIdx.x;

    #pragma unroll
    for (int i = 0; i < 16; ++i) {
        int idx = i * 256 + t;
        int j = idx >> 5, k4 = idx & 31;
        Ws4[(j << 5) | (k4 ^ (j & 31))] = Wg4[idx];
    }
    __syncthreads();

    const int lane  = t & 63;
    const int w     = __builtin_amdgcn_readfirstlane(t >> 6);
    const int node0 = blockIdx.x * 32 + w * 8;

    const float4* u4 = reinterpret_cast<const float4*>(u);
    const float4* up[8];
    #pragma unroll
    for (int nn = 0; nn < 8; ++nn) {
        int n = node0 + nn; if (n > NN - 1) n = NN - 1;
        up[nn] = u4 + (size_t)n * 32;
    }

    float a0[8], a1[8];
    #pragma unroll
    for (int nn = 0; nn < 8; ++nn) { a0[nn] = 0.f; a1[nn] = 0.f; }

    const int sw = lane & 31;
    #pragma unroll 2
    for (int k4 = 0; k4 < 32; ++k4) {
        float4 w0 = Ws4[(lane << 5)        | (k4 ^ sw)];
        float4 w1 = Ws4[((lane + 64) << 5) | (k4 ^ sw)];
        #pragma unroll
        for (int nn = 0; nn < 8; ++nn) {
            float4 xv = up[nn][k4];
            a0[nn] += w0.x * xv.x + w0.y * xv.y + w0.z * xv.z + w0.w * xv.w;
            a1[nn] += w1.x * xv.x + w1.y * xv.y + w1.z * xv.z + w1.w * xv.w;
        }
    }

    const float b0 = Ob[lane], b1 = Ob[lane + 64];

    #pragma unroll
    for (int nn = 0; nn < 8; ++nn) {
        int n = node0 + nn;
        if (n < NN) {
            out[(size_t)n * 128 + lane]      = a0[nn] + b0 + u[(size_t)n * 128 + lane];
            out[(size_t)n * 128 + lane + 64] = a1[nn] + b1 + u[(size_t)n * 128 + lane + 64];
        }
    }
}

// ---------------------------------------------------------------------------
extern "C" void kernel_launch(void* const* d_in, const int* in_sizes, int n_in,
                              void* d_out, int out_size, void* d_ws, size_t ws_size,
                              hipStream_t stream) {
    const float* x     = (const float*)d_in[0];
    const int*   src   = (const int*)d_in[1];
    const int*   dst   = (const int*)d_in[2];
    const float* local = (const float*)d_in[3];
    const int*   ts    = (const int*)d_in[4];
    const float* gam   = (const float*)d_in[5];
    const float* eta   = (const float*)d_in[6];
    const float* xi    = (const float*)d_in[7];
    const float* Ww    = (const float*)d_in[8];
    const float* Wb    = (const float*)d_in[9];
    const float* lng   = (const float*)d_in[10];
    const float* lnb   = (const float*)d_in[11];
    const float* Ow    = (const float*)d_in[12];
    const float* Ob    = (const float*)d_in[13];
    float* out = (float*)d_out;

    float* m   = (float*)d_ws;                    // [NN,128]  (reused as u later)
    float* agg = m + (size_t)NN * 128;            // [NN,128]

    hipMemsetAsync(agg, 0, sizeof(float) * (size_t)NN * 128, stream);

    const int tiles = (NN + 31) / 32;             // 1563
    node_msg_kernel<<<tiles, 256, 0, stream>>>(x, Ww, Wb, lng, lnb, ts, gam, eta, m);
    edge_scatter_kernel<<<(NE * 32) / 256, 256, 0, stream>>>(m, src, dst, agg);
    upd_kernel<<<(NN * 32 + 255) / 256, 256, 0, stream>>>(x, agg, local, xi, m); // u -> m
    out_gemm_kernel<<<tiles, 256, 0, stream>>>(m, Ow, Ob, out);
}

// Round 2
// 254.835 us; speedup vs baseline: 4.5449x; 4.5449x over previous
//
#include <hip/hip_runtime.h>

#define NN 50000
#define NE 600000
#define LN_EPS 1e-5f

// ---------------------------------------------------------------------------
// K1: per-node message  m[n] = s * (LN(x[n] @ W.T + Wb) * ln_g + ln_b)
//     s = sigmoid(gamma[t]) * (1 - sigmoid(eta[t]))
// ---------------------------------------------------------------------------
__global__ __launch_bounds__(256)
void node_msg_kernel(const float* __restrict__ x, const float* __restrict__ Ww,
                     const float* __restrict__ Wb, const float* __restrict__ lng,
                     const float* __restrict__ lnb, const int* __restrict__ ts,
                     const float* __restrict__ gam, const float* __restrict__ eta,
                     float* __restrict__ m)
{
    __shared__ float Ws[128 * 128];              // 64 KiB
    float4* Ws4 = reinterpret_cast<float4*>(Ws);
    const float4* Wg4 = reinterpret_cast<const float4*>(Ww);
    const int t = threadIdx.x;

    #pragma unroll
    for (int i = 0; i < 16; ++i) {
        int idx = i * 256 + t;
        int j = idx >> 5, k4 = idx & 31;
        Ws4[(j << 5) | (k4 ^ (j & 31))] = Wg4[idx];
    }
    __syncthreads();

    const int lane  = t & 63;
    const int w     = __builtin_amdgcn_readfirstlane(t >> 6);
    const int node0 = blockIdx.x * 32 + w * 8;

    const float4* x4 = reinterpret_cast<const float4*>(x);
    const float4* xp[8];
    #pragma unroll
    for (int nn = 0; nn < 8; ++nn) {
        int n = node0 + nn; if (n > NN - 1) n = NN - 1;
        xp[nn] = x4 + (size_t)n * 32;
    }

    float a0[8], a1[8];
    #pragma unroll
    for (int nn = 0; nn < 8; ++nn) { a0[nn] = 0.f; a1[nn] = 0.f; }

    const int sw = lane & 31;
    #pragma unroll 2
    for (int k4 = 0; k4 < 32; ++k4) {
        float4 w0 = Ws4[(lane << 5)        | (k4 ^ sw)];
        float4 w1 = Ws4[((lane + 64) << 5) | (k4 ^ sw)];
        #pragma unroll
        for (int nn = 0; nn < 8; ++nn) {
            float4 xv = xp[nn][k4];
            a0[nn] += w0.x * xv.x + w0.y * xv.y + w0.z * xv.z + w0.w * xv.w;
            a1[nn] += w1.x * xv.x + w1.y * xv.y + w1.z * xv.z + w1.w * xv.w;
        }
    }

    const int tstep = ts[0];
    const float gsig = 1.f / (1.f + __expf(-gam[tstep]));
    const float esig = 1.f / (1.f + __expf(-eta[tstep]));
    const float sgate = gsig * (1.f - esig);

    const float b0 = Wb[lane],  b1 = Wb[lane + 64];
    const float g0 = lng[lane], g1 = lng[lane + 64];
    const float e0 = lnb[lane], e1 = lnb[lane + 64];

    #pragma unroll
    for (int nn = 0; nn < 8; ++nn) {
        float h0 = a0[nn] + b0, h1 = a1[nn] + b1;
        float r = h0 + h1, r2 = h0 * h0 + h1 * h1;
        #pragma unroll
        for (int mk = 1; mk < 64; mk <<= 1) {
            r  += __shfl_xor(r,  mk, 64);
            r2 += __shfl_xor(r2, mk, 64);
        }
        float mu  = r * (1.f / 128.f);
        float var = r2 * (1.f / 128.f) - mu * mu;
        float rs  = rsqrtf(var + LN_EPS);
        int n = node0 + nn;
        if (n < NN) {
            m[(size_t)n * 128 + lane]      = sgate * ((h0 - mu) * rs * g0 + e0);
            m[(size_t)n * 128 + lane + 64] = sgate * ((h1 - mu) * rs * g1 + e1);
        }
    }
}

// ---------------------------------------------------------------------------
// CSR build: histogram -> single-block scan -> counting-sort scatter
// ---------------------------------------------------------------------------
__global__ __launch_bounds__(256)
void hist_kernel(const int* __restrict__ dst, int* __restrict__ cnt)
{
    int e = blockIdx.x * 256 + threadIdx.x;
    if (e < NE) atomicAdd(&cnt[dst[e]], 1);
}

#define SCAN_T 1024
#define EPT 8
__global__ __launch_bounds__(1024)
void scan_kernel(const int* __restrict__ cnt, int* __restrict__ offs,
                 int* __restrict__ cursor)
{
    __shared__ int wsum[16];
    __shared__ int s_carry;
    const int tid = threadIdx.x;
    const int lane = tid & 63, wid = tid >> 6;
    if (tid == 0) s_carry = 0;
    __syncthreads();

    for (int base = 0; base < NN; base += SCAN_T * EPT) {
        int v[EPT];
        const int i0 = base + tid * EPT;
        #pragma unroll
        for (int k = 0; k < EPT; ++k) {
            int i = i0 + k;
            v[k] = (i < NN) ? cnt[i] : 0;
        }
        int tsum = 0;
        #pragma unroll
        for (int k = 0; k < EPT; ++k) tsum += v[k];

        int incl = tsum;                          // wave inclusive scan
        #pragma unroll
        for (int d = 1; d < 64; d <<= 1) {
            int o = __shfl_up(incl, d, 64);
            if (lane >= d) incl += o;
        }
        if (lane == 63) wsum[wid] = incl;
        __syncthreads();
        if (wid == 0) {
            int wv = (lane < 16) ? wsum[lane] : 0;
            int wincl = wv;
            #pragma unroll
            for (int d = 1; d < 16; d <<= 1) {
                int o = __shfl_up(wincl, d, 64);
                if (lane >= d) wincl += o;
            }
            if (lane < 16) wsum[lane] = wincl - wv;   // exclusive wave prefix
        }
        __syncthreads();
        int run = s_carry + wsum[wid] + (incl - tsum);
        #pragma unroll
        for (int k = 0; k < EPT; ++k) {
            int i = i0 + k;
            if (i < NN) { offs[i] = run; cursor[i] = run; }
            run += v[k];
        }
        __syncthreads();                           // all read s_carry first
        if (tid == SCAN_T - 1) s_carry = run;      // carry + chunk total
        __syncthreads();
    }
    if (tid == 0) offs[NN] = s_carry;              // == NE
}

__global__ __launch_bounds__(256)
void sort_scatter_kernel(const int* __restrict__ src, const int* __restrict__ dst,
                         int* __restrict__ cursor, int* __restrict__ ssorted)
{
    int e = blockIdx.x * 256 + threadIdx.x;
    if (e < NE) {
        int pos = atomicAdd(&cursor[dst[e]], 1);
        ssorted[pos] = src[e];
    }
}

// ---------------------------------------------------------------------------
// Fused gather + update: one wave per node.
//   u[n] = relu(x[n] + sum_{e: dst=n} m[src[e]] + xi*local[n])   -> d_out
// ---------------------------------------------------------------------------
__global__ __launch_bounds__(256)
void gather_upd_kernel(const float* __restrict__ m, const int* __restrict__ offs,
                       const int* __restrict__ ssorted, const float* __restrict__ x,
                       const float* __restrict__ local, const float* __restrict__ xi,
                       float* __restrict__ u)
{
    const int wave = (blockIdx.x * 256 + threadIdx.x) >> 6;
    const int lane = threadIdx.x & 63;
    if (wave >= NN) return;

    const int start = offs[wave], end = offs[wave + 1];
    const float2* m2 = reinterpret_cast<const float2*>(m);

    float ax = 0.f, ay = 0.f;
    int o = start;
    for (; o + 1 < end; o += 2) {
        int s0 = ssorted[o], s1 = ssorted[o + 1];
        float2 v0 = m2[(size_t)s0 * 64 + lane];
        float2 v1 = m2[(size_t)s1 * 64 + lane];
        ax += v0.x + v1.x;
        ay += v0.y + v1.y;
    }
    if (o < end) {
        int s = ssorted[o];
        float2 v = m2[(size_t)s * 64 + lane];
        ax += v.x; ay += v.y;
    }

    const float xiv = xi[0];
    float2 xv = reinterpret_cast<const float2*>(x)[(size_t)wave * 64 + lane];
    float2 lv = reinterpret_cast<const float2*>(local)[(size_t)wave * 64 + lane];
    float2 r;
    r.x = fmaxf(xv.x + ax + xiv * lv.x, 0.f);
    r.y = fmaxf(xv.y + ay + xiv * lv.y, 0.f);
    reinterpret_cast<float2*>(u)[(size_t)wave * 64 + lane] = r;
}

// ---------------------------------------------------------------------------
// K4: out = u @ out_w.T + out_b + u, IN-PLACE on u (= d_out).
// Row n of out depends only on row n of u; residual captured in registers
// before any store; each wave reads only its own 8 rows.
// ---------------------------------------------------------------------------
__global__ __launch_bounds__(256)
void out_gemm_kernel(float* __restrict__ u_out, const float* __restrict__ Ow,
                     const float* __restrict__ Ob)
{
    __shared__ float Ws[128 * 128];
    float4* Ws4 = reinterpret_cast<float4*>(Ws);
    const float4* Wg4 = reinterpret_cast<const float4*>(Ow);
    const int t = threadIdx.x;

    #pragma unroll
    for (int i = 0; i < 16; ++i) {
        int idx = i * 256 + t;
        int j = idx >> 5, k4 = idx & 31;
        Ws4[(j << 5) | (k4 ^ (j & 31))] = Wg4[idx];
    }
    __syncthreads();

    const int lane  = t & 63;
    const int w     = __builtin_amdgcn_readfirstlane(t >> 6);
    const int node0 = blockIdx.x * 32 + w * 8;

    const float4* u4 = reinterpret_cast<const float4*>(u_out);
    const float4* up[8];
    float res0[8], res1[8];
    #pragma unroll
    for (int nn = 0; nn < 8; ++nn) {
        int n = node0 + nn; if (n > NN - 1) n = NN - 1;
        up[nn] = u4 + (size_t)n * 32;
        res0[nn] = u_out[(size_t)n * 128 + lane];
        res1[nn] = u_out[(size_t)n * 128 + lane + 64];
    }

    float a0[8], a1[8];
    #pragma unroll
    for (int nn = 0; nn < 8; ++nn) { a0[nn] = 0.f; a1[nn] = 0.f; }

    const int sw = lane & 31;
    #pragma unroll 2
    for (int k4 = 0; k4 < 32; ++k4) {
        float4 w0 = Ws4[(lane << 5)        | (k4 ^ sw)];
        float4 w1 = Ws4[((lane + 64) << 5) | (k4 ^ sw)];
        #pragma unroll
        for (int nn = 0; nn < 8; ++nn) {
            float4 xv = up[nn][k4];
            a0[nn] += w0.x * xv.x + w0.y * xv.y + w0.z * xv.z + w0.w * xv.w;
            a1[nn] += w1.x * xv.x + w1.y * xv.y + w1.z * xv.z + w1.w * xv.w;
        }
    }

    const float b0 = Ob[lane], b1 = Ob[lane + 64];

    #pragma unroll
    for (int nn = 0; nn < 8; ++nn) {
        int n = node0 + nn;
        if (n < NN) {
            u_out[(size_t)n * 128 + lane]      = a0[nn] + b0 + res0[nn];
            u_out[(size_t)n * 128 + lane + 64] = a1[nn] + b1 + res1[nn];
        }
    }
}

// ---------------------------------------------------------------------------
extern "C" void kernel_launch(void* const* d_in, const int* in_sizes, int n_in,
                              void* d_out, int out_size, void* d_ws, size_t ws_size,
                              hipStream_t stream) {
    const float* x     = (const float*)d_in[0];
    const int*   src   = (const int*)d_in[1];
    const int*   dst   = (const int*)d_in[2];
    const float* local = (const float*)d_in[3];
    const int*   ts    = (const int*)d_in[4];
    const float* gam   = (const float*)d_in[5];
    const float* eta   = (const float*)d_in[6];
    const float* xi    = (const float*)d_in[7];
    const float* Ww    = (const float*)d_in[8];
    const float* Wb    = (const float*)d_in[9];
    const float* lng   = (const float*)d_in[10];
    const float* lnb   = (const float*)d_in[11];
    const float* Ow    = (const float*)d_in[12];
    const float* Ob    = (const float*)d_in[13];
    float* out = (float*)d_out;

    float* m      = (float*)d_ws;                 // [NN,128] = 25.6 MB
    int*   cnt    = (int*)(m + (size_t)NN * 128); // NN
    int*   offs   = cnt + NN;                     // NN+1
    int*   cursor = offs + NN + 1;                // NN
    int*   ssort  = cursor + NN;                  // NE

    hipMemsetAsync(cnt, 0, sizeof(int) * NN, stream);

    const int tiles = (NN + 31) / 32;             // 1563
    node_msg_kernel<<<tiles, 256, 0, stream>>>(x, Ww, Wb, lng, lnb, ts, gam, eta, m);
    hist_kernel<<<(NE + 255) / 256, 256, 0, stream>>>(dst, cnt);
    scan_kernel<<<1, 1024, 0, stream>>>(cnt, offs, cursor);
    sort_scatter_kernel<<<(NE + 255) / 256, 256, 0, stream>>>(src, dst, cursor, ssort);
    gather_upd_kernel<<<(NN * 64 + 255) / 256, 256, 0, stream>>>(m, offs, ssort, x, local, xi, out);
    out_gemm_kernel<<<tiles, 256, 0, stream>>>(out, Ow, Ob);
}